// Round 1
// baseline (786.235 us; speedup 1.0000x reference)
//
#include <hip/hip_runtime.h>
#include <math.h>

// Problem: x [8,128,256,256] f32, weights [128] f32.
// out[b,i,h,w] = (softmax(weights)*128)[rank(i within column)] * rsqrt(x^2+eps)
// rank = stable descending rank along axis 1:
//   rank[i] = #{j<i: x[j] >= x[i]} + #{j>i: x[j] > x[i]}
// Exact tie semantics required (stable argsort of argsort).

#define Q    128
#define TCOL 64
#define HW   65536            // 256*256; stride along axis 1 in floats
#define EPSF 1e-6f

__launch_bounds__(256, 4)
__global__ void rank_weight_kernel(const float* __restrict__ x,
                                   const float* __restrict__ weights,
                                   float* __restrict__ out) {
    __shared__ float lds_x[Q][TCOL];   // 32 KB tile: [row q][col], conflict-free
    __shared__ float lds_wt[Q];        // softmax(weights)*Q

    const int tid = threadIdx.x;
    const int g   = blockIdx.x;            // column-group id (64 cols each)
    const int b   = g >> 10;               // 65536/64 = 1024 groups per batch
    const int hw0 = (g & 1023) << 6;       // first hw of this group (16B aligned)
    const float* xb = x   + (size_t)b * Q * HW + hw0;
    float*       ob = out + (size_t)b * Q * HW + hw0;

    // ---- stage 128x64 tile into LDS: 2048 float4, 8 per thread, coalesced ----
    for (int f = tid; f < Q * (TCOL / 4); f += 256) {
        const int r = f >> 4;          // row (q index)
        const int p = f & 15;          // float4 slot within row
        float4 val = *reinterpret_cast<const float4*>(xb + (size_t)r * HW + (p << 2));
        *reinterpret_cast<float4*>(&lds_x[r][p << 2]) = val;
    }

    // ---- softmax(weights) * 128 by wave 0 (single wave, shfl reductions) ----
    if (tid < 64) {
        float w0 = weights[tid];
        float w1 = weights[tid + 64];
        float m = fmaxf(w0, w1);
        #pragma unroll
        for (int off = 32; off; off >>= 1) m = fmaxf(m, __shfl_xor(m, off, 64));
        float e0 = __expf(w0 - m), e1 = __expf(w1 - m);
        float s = e0 + e1;
        #pragma unroll
        for (int off = 32; off; off >>= 1) s += __shfl_xor(s, off, 64);
        float scale = 128.0f / s;
        lds_wt[tid]      = e0 * scale;
        lds_wt[tid + 64] = e1 * scale;
    }
    __syncthreads();

    const int wave = tid >> 6;   // i-range owner: rows [wave*32, wave*32+32)
    const int c    = tid & 63;   // column within tile

    for (int ci = 0; ci < 4; ++ci) {
        const int i0 = wave * 32 + ci * 8;   // wave-uniform

        float v[8];
        #pragma unroll
        for (int u = 0; u < 8; ++u) v[u] = lds_x[i0 + u][c];
        int rk[8];
        #pragma unroll
        for (int u = 0; u < 8; ++u) rk[u] = 0;

        // j < i0 : count (w >= v)   (i0 is a multiple of 8)
        for (int j = 0; j < i0; j += 8) {
            #pragma unroll
            for (int jj = 0; jj < 8; ++jj) {
                float w = lds_x[j + jj][c];
                #pragma unroll
                for (int u = 0; u < 8; ++u) rk[u] += (w >= v[u]);
            }
        }
        // diagonal 8x8 block: register-register, compile-time j/i relation
        #pragma unroll
        for (int ju = 0; ju < 8; ++ju) {
            #pragma unroll
            for (int u = 0; u < 8; ++u) {
                if (ju < u)      rk[u] += (v[ju] >= v[u]);
                else if (ju > u) rk[u] += (v[ju] >  v[u]);
            }
        }
        // j > i0+7 : count (w > v)   ((128 - i0 - 8) is a multiple of 8)
        for (int j = i0 + 8; j < Q; j += 8) {
            #pragma unroll
            for (int jj = 0; jj < 8; ++jj) {
                float w = lds_x[j + jj][c];
                #pragma unroll
                for (int u = 0; u < 8; ++u) rk[u] += (w > v[u]);
            }
        }

        // epilogue: gather weight by rank, apply rsqrt, coalesced store
        #pragma unroll
        for (int u = 0; u < 8; ++u) {
            float wt  = lds_wt[rk[u]];
            float val = v[u];
            ob[(size_t)(i0 + u) * HW + c] = wt * rsqrtf(val * val + EPSF);
        }
    }
}

extern "C" void kernel_launch(void* const* d_in, const int* in_sizes, int n_in,
                              void* d_out, int out_size, void* d_ws, size_t ws_size,
                              hipStream_t stream) {
    const float* x  = (const float*)d_in[0];
    const float* wt = (const float*)d_in[1];
    float* out      = (float*)d_out;

    // 8 batches * 65536 hw = 524288 columns / 64 per block = 8192 blocks
    dim3 grid(8192), block(256);
    hipLaunchKernelGGL(rank_weight_kernel, grid, block, 0, stream, x, wt, out);
}

// Round 2
// 772.800 us; speedup vs baseline: 1.0174x; 1.0174x over previous
//
#include <hip/hip_runtime.h>
#include <math.h>

// Problem: x [8,128,256,256] f32, weights [128] f32.
// out[b,i,h,w] = (softmax(weights)*128)[rank(i within column)] * rsqrt(x^2+eps)
// rank[i] = #{j<i: x[j] >= x[i]} + #{j>i: x[j] > x[i]}  (stable descending rank)
//
// R2: force 2-VALU-op compare-accumulate (v_cmp to sgpr pair + v_addc) via
// inline asm; widen per-wave row block to 32 (4x fewer LDS reads); symmetric
// 3-op updates for the in-register 32x32 diagonal block.

#define Q    128
#define TCOL 64
#define HW   65536
#define EPSF 1e-6f

// rk += (a >= b)   -- 2 VALU ops, independent sgpr-pair carry
__device__ __forceinline__ void acc_ge(int& rk, float a, float b) {
    unsigned long long c, dead;
    asm("v_cmp_ge_f32 %0, %1, %2" : "=s"(c) : "v"(a), "v"(b));
    asm("v_addc_co_u32 %0, %1, %0, 0, %2" : "+v"(rk), "=s"(dead) : "s"(c));
}
// rk += (a > b)
__device__ __forceinline__ void acc_gt(int& rk, float a, float b) {
    unsigned long long c, dead;
    asm("v_cmp_gt_f32 %0, %1, %2" : "=s"(c) : "v"(a), "v"(b));
    asm("v_addc_co_u32 %0, %1, %0, 0, %2" : "+v"(rk), "=s"(dead) : "s"(c));
}
// c = (va >= vb); rkb += c; rka -= c;   -- 3 VALU ops for an unordered pair
__device__ __forceinline__ void pair_upd(int& rkb, int& rka, float va, float vb) {
    unsigned long long c, d1, d2;
    asm("v_cmp_ge_f32 %0, %1, %2" : "=s"(c) : "v"(va), "v"(vb));
    asm("v_addc_co_u32 %0, %1, %0, 0, %2" : "+v"(rkb), "=s"(d1) : "s"(c));
    asm("v_subb_co_u32 %0, %1, %0, 0, %2" : "+v"(rka), "=s"(d2) : "s"(c));
}

__launch_bounds__(256, 4)
__global__ void rank_weight_kernel(const float* __restrict__ x,
                                   const float* __restrict__ weights,
                                   float* __restrict__ out) {
    __shared__ float lds_x[Q][TCOL];   // 32 KB: [row q][col]; b32 reads 2-way/bank = free
    __shared__ float lds_wt[Q];        // softmax(weights)*Q

    const int tid = threadIdx.x;
    const int g   = blockIdx.x;
    const int b   = g >> 10;               // 1024 groups of 64 hw per batch
    const int hw0 = (g & 1023) << 6;
    const float* xb = x   + (size_t)b * Q * HW + hw0;
    float*       ob = out + (size_t)b * Q * HW + hw0;

    // stage 128x64 tile: 2048 float4, coalesced
    for (int f = tid; f < Q * (TCOL / 4); f += 256) {
        const int r = f >> 4;
        const int p = f & 15;
        float4 val = *reinterpret_cast<const float4*>(xb + (size_t)r * HW + (p << 2));
        *reinterpret_cast<float4*>(&lds_x[r][p << 2]) = val;
    }

    // softmax(weights) * 128 by wave 0
    if (tid < 64) {
        float w0 = weights[tid];
        float w1 = weights[tid + 64];
        float m = fmaxf(w0, w1);
        #pragma unroll
        for (int off = 32; off; off >>= 1) m = fmaxf(m, __shfl_xor(m, off, 64));
        float e0 = __expf(w0 - m), e1 = __expf(w1 - m);
        float s = e0 + e1;
        #pragma unroll
        for (int off = 32; off; off >>= 1) s += __shfl_xor(s, off, 64);
        float scale = 128.0f / s;
        lds_wt[tid]      = e0 * scale;
        lds_wt[tid + 64] = e1 * scale;
    }
    __syncthreads();

    const int wave = tid >> 6;   // owns rows [R0, R0+32)
    const int c    = tid & 63;
    const int R0   = wave * 32;

    // load this wave's 32 row values; init rank with within-block "later rows" count
    float v[32];
    int   rk[32];
    #pragma unroll
    for (int u = 0; u < 32; ++u) v[u] = lds_x[R0 + u][c];
    #pragma unroll
    for (int u = 0; u < 32; ++u) rk[u] = 31 - u;

    // ---- in-register 32x32 diagonal block: 496 unordered pairs, 3 ops each ----
    // for a<b: c=(v[a]>=v[b]); rank[R0+b] += c (j<i, >=); rank[R0+a] += (1-c) (j>i, >)
    #pragma unroll
    for (int a = 0; a < 32; ++a) {
        #pragma unroll
        for (int bq = a + 1; bq < 32; ++bq) pair_upd(rk[bq], rk[a], v[a], v[bq]);
    }

    // ---- j < R0 : count (w >= v), streamed from LDS ----
    for (int j = 0; j < R0; j += 2) {
        float w0 = lds_x[j][c];
        float w1 = lds_x[j + 1][c];
        #pragma unroll
        for (int u = 0; u < 32; ++u) acc_ge(rk[u], w0, v[u]);
        #pragma unroll
        for (int u = 0; u < 32; ++u) acc_ge(rk[u], w1, v[u]);
    }
    // ---- j >= R0+32 : count (w > v) ----
    for (int j = R0 + 32; j < Q; j += 2) {
        float w0 = lds_x[j][c];
        float w1 = lds_x[j + 1][c];
        #pragma unroll
        for (int u = 0; u < 32; ++u) acc_gt(rk[u], w0, v[u]);
        #pragma unroll
        for (int u = 0; u < 32; ++u) acc_gt(rk[u], w1, v[u]);
    }

    // ---- epilogue: gather weight by rank, coalesced store per row ----
    #pragma unroll
    for (int u = 0; u < 32; ++u) {
        float wt  = lds_wt[rk[u]];
        float val = v[u];
        ob[(size_t)(R0 + u) * HW + c] = wt * rsqrtf(val * val + EPSF);
    }
}

extern "C" void kernel_launch(void* const* d_in, const int* in_sizes, int n_in,
                              void* d_out, int out_size, void* d_ws, size_t ws_size,
                              hipStream_t stream) {
    const float* x  = (const float*)d_in[0];
    const float* wt = (const float*)d_in[1];
    float* out      = (float*)d_out;

    dim3 grid(8192), block(256);   // 524288 columns / 64 per block
    hipLaunchKernelGGL(rank_weight_kernel, grid, block, 0, stream, x, wt, out);
}